// Round 5
// baseline (202.383 us; speedup 1.0000x reference)
//
#include <hip/hip_runtime.h>
#include <hip/hip_bf16.h>

#define T_TOT 2304
#define DDIM  1024
#define NH    16
#define DK    64
#define SLEN  128
#define SEQ   2048

typedef __bf16 bf16x8 __attribute__((ext_vector_type(8)));
typedef __bf16 bf16x4 __attribute__((ext_vector_type(4)));
typedef float  f32x4  __attribute__((ext_vector_type(4)));

__device__ __forceinline__ void async_copy16(const void* gsrc, void* ldst) {
  __builtin_amdgcn_global_load_lds(
      (const __attribute__((address_space(1))) void*)gsrc,
      (__attribute__((address_space(3))) void*)ldst, 16, 0, 0);
}

// ---------------- convert: x -> bf16 (vectorized); W[h][d][n] -> Wt[m][h][n][d] via LDS transpose
__global__ __launch_bounds__(256) void convert_kernel(
    const float* __restrict__ x,
    const float* __restrict__ Wq, const float* __restrict__ Wk,
    const float* __restrict__ Wv, const float* __restrict__ Wqs,
    const float* __restrict__ Wks, const float* __restrict__ Wvs,
    __bf16* __restrict__ xb, __bf16* __restrict__ Wt) {
  const int b = blockIdx.x;
  const int tid = threadIdx.x;
  if (b < 576) {
    const float4* xin = (const float4*)x;
#pragma unroll
    for (int it = 0; it < 4; ++it) {
      int idx4 = b * 1024 + it * 256 + tid;
      float4 v = xin[idx4];
      bf16x4 o;
      o[0] = (__bf16)v.x; o[1] = (__bf16)v.y; o[2] = (__bf16)v.z; o[3] = (__bf16)v.w;
      *(bf16x4*)(xb + (size_t)idx4 * 4) = o;
    }
    return;
  }
  __shared__ float tile[64 * 65];
  const int wb = b - 576;
  const int m  = wb >> 8;
  const int rem = wb & 255;
  const int h  = rem >> 4;
  const int dt = rem & 15;
  const int d0 = dt * 64;
  const float* Wsrc = (m == 0 ? Wq : m == 1 ? Wk : m == 2 ? Wv
                      : m == 3 ? Wqs : m == 4 ? Wks : Wvs) + (size_t)h * (DDIM * DK);
#pragma unroll
  for (int rr = 0; rr < 4; ++rr) {
    int drow = rr * 16 + (tid >> 4);
    int nc   = (tid & 15) * 4;
    float4 v = *(const float4*)(Wsrc + (size_t)(d0 + drow) * DK + nc);
    tile[(nc + 0) * 65 + drow] = v.x;
    tile[(nc + 1) * 65 + drow] = v.y;
    tile[(nc + 2) * 65 + drow] = v.z;
    tile[(nc + 3) * 65 + drow] = v.w;
  }
  __syncthreads();
  {
    int n  = tid >> 2;
    int rg = (tid & 3) * 16;
    __bf16* dst = Wt + (((size_t)(m * NH + h)) * DK + n) * DDIM + d0 + rg;
    bf16x8 o0, o1;
#pragma unroll
    for (int e = 0; e < 8; e++) o0[e] = (__bf16)tile[n * 65 + rg + e];
#pragma unroll
    for (int e = 0; e < 8; e++) o1[e] = (__bf16)tile[n * 65 + rg + 8 + e];
    *(bf16x8*)dst = o0;
    *(bf16x8*)(dst + 8) = o1;
  }
}

// ---------------- projection + l2norm, BK=128; launch_bounds(256,2) frees registers
__global__ __launch_bounds__(256, 2) void proj_kernel(
    const __bf16* __restrict__ xb, const __bf16* __restrict__ Wt,
    const float* __restrict__ scal,
    __bf16* __restrict__ qkv, __bf16* __restrict__ vt) {
  const int which = blockIdx.x;
  const int rt    = blockIdx.y;
  const int h     = blockIdx.z;
  const int r0    = rt * 128;
  const int m     = (rt == 0 || rt == 17) ? which + 3 : which;

  __shared__ __bf16 Xs[128 * 128];   // 32 KB
  __shared__ __bf16 Wsh[64 * 128];   // 16 KB

  const int tid  = threadIdx.x;
  const int wave = tid >> 6, lane = tid & 63;
  const int quad = lane >> 4, lc = lane & 15;

  const __bf16* Wbase = Wt + ((size_t)(m * NH + h)) * (DK * DDIM);

  const f32x4 fz = {0.f, 0.f, 0.f, 0.f};
  f32x4 acc[2][4];
#pragma unroll
  for (int i = 0; i < 2; i++)
#pragma unroll
    for (int j = 0; j < 4; j++) acc[i][j] = fz;

  for (int k0 = 0; k0 < DDIM; k0 += 128) {
#pragma unroll
    for (int it = 0; it < 8; ++it) {
      int L = it * 256 + tid;
      int row = L >> 4, c = (L & 15) ^ ((L >> 4) & 15);
      async_copy16(xb + (size_t)(r0 + row) * DDIM + k0 + c * 8,
                   (char*)Xs + (size_t)(it * 256 + wave * 64) * 16);
    }
#pragma unroll
    for (int it = 0; it < 4; ++it) {
      int L = it * 256 + tid;
      int row = L >> 4, c = (L & 15) ^ ((L >> 4) & 15);
      async_copy16(Wbase + (size_t)row * DDIM + k0 + c * 8,
                   (char*)Wsh + (size_t)(it * 256 + wave * 64) * 16);
    }
    __syncthreads();
#pragma unroll
    for (int kk = 0; kk < 4; kk++) {
      bf16x8 afr[2], bfr[4];
#pragma unroll
      for (int i = 0; i < 2; i++) {
        int row = wave * 32 + i * 16 + lc;
        int ch  = (kk * 4 + quad) ^ (row & 15);
        afr[i] = *(const bf16x8*)(Xs + (row * 16 + ch) * 8);
      }
#pragma unroll
      for (int j = 0; j < 4; j++) {
        int row = j * 16 + lc;
        int ch  = (kk * 4 + quad) ^ (row & 15);
        bfr[j] = *(const bf16x8*)(Wsh + (row * 16 + ch) * 8);
      }
#pragma unroll
      for (int i = 0; i < 2; i++)
#pragma unroll
        for (int j = 0; j < 4; j++)
          acc[i][j] = __builtin_amdgcn_mfma_f32_16x16x32_bf16(afr[i], bfr[j], acc[i][j], 0, 0, 0);
    }
    __syncthreads();
  }

  float inv4[2][4];
  const float qscale = (which == 0) ? scal[h] : 1.0f;
#pragma unroll
  for (int i = 0; i < 2; i++) {
#pragma unroll
    for (int r = 0; r < 4; r++) {
      float s = 0.f;
#pragma unroll
      for (int j = 0; j < 4; j++) { float v = acc[i][j][r]; s += v * v; }
#pragma unroll
      for (int off = 1; off < 16; off <<= 1) s += __shfl_xor(s, off, 64);
      inv4[i][r] = qscale / fmaxf(sqrtf(s), 1e-12f);
    }
  }
  if (which == 2) {
    __bf16* vtp = vt + (size_t)h * (DK * T_TOT);
#pragma unroll
    for (int i = 0; i < 2; i++) {
      int rowbase = r0 + wave * 32 + i * 16 + quad * 4;
#pragma unroll
      for (int j = 0; j < 4; j++) {
        bf16x4 o;
#pragma unroll
        for (int r = 0; r < 4; r++) o[r] = (__bf16)(acc[i][j][r] * inv4[i][r]);
        *(bf16x4*)(vtp + (size_t)(j * 16 + lc) * T_TOT + rowbase) = o;
      }
    }
  } else {
    __bf16* outp = qkv + ((size_t)(which * NH + h)) * ((size_t)T_TOT * DK);
#pragma unroll
    for (int i = 0; i < 2; i++)
#pragma unroll
      for (int r = 0; r < 4; r++) {
        int row = r0 + wave * 32 + i * 16 + quad * 4 + r;
#pragma unroll
        for (int j = 0; j < 4; j++)
          outp[(size_t)row * DK + j * 16 + lc] = (__bf16)(acc[i][j][r] * inv4[i][r]);
      }
  }
}

// ---------------- flash attention v5: S^T, BN=128, 4-way kv split, register-rich
// launch_bounds(256,2): ~200 live VGPRs so all 32 loads/iter stay in flight.
__global__ __launch_bounds__(256, 2) void attn_kernel(
    const __bf16* __restrict__ qkv, const __bf16* __restrict__ vt,
    float* __restrict__ out) {
  const int b    = blockIdx.x;          // 0..2303
  const int h    = b & 15;
  const int qt   = 143 - (b >> 4);      // big work first
  const int q0w  = qt * 16;
  const int tid  = threadIdx.x;
  const int wave = tid >> 6, lane = tid & 63;
  const int quad = lane >> 4, lc = lane & 15;

  const __bf16* qp = qkv + ((size_t)h) * ((size_t)T_TOT * DK);
  const __bf16* kp = qkv + ((size_t)(NH + h)) * ((size_t)T_TOT * DK);
  const __bf16* vp = vt + (size_t)h * (DK * T_TOT);

  __shared__ __bf16 Ps[4][16 * 128];    // per-wave P tile [q][kv], swizzled 16B chunks
  __shared__ float  OL[3][1024];        // waves 1..3 O^T for merge
  __shared__ float  mlL[3][2][16];

  // Q B-frag (persistent)
  bf16x8 qf[2];
#pragma unroll
  for (int kk = 0; kk < 2; kk++)
    qf[kk] = *(const bf16x8*)(qp + (size_t)(q0w + lc) * DK + kk * 32 + quad * 8);

  const f32x4 fz = {0.f, 0.f, 0.f, 0.f};
  f32x4 acc_o[4];                       // O^T: d = ct*16+quad*4+r, q = lc
#pragma unroll
  for (int ct = 0; ct < 4; ct++) acc_o[ct] = fz;
  float m_i = -__builtin_inff(), l_i = 0.f;

  const int ustart = (q0w >= SLEN + SEQ) ? 1 : 0;
  const int uend   = q0w >> 7;
  const int nu     = uend - ustart + 1;
  const int b0     = ustart + ((nu * wave) >> 2);
  const int b1     = ustart + ((nu * (wave + 1)) >> 2);

  for (int u = b0; u < b1; ++u) {
    const int c0 = u * 128;
    const bool diag = (u == uend);

    // ---- issue ALL loads up front (32 in flight; scoreboard pipelines MFMAs)
    bf16x8 kA[8][2];
#pragma unroll
    for (int ct = 0; ct < 8; ct++)
#pragma unroll
      for (int kk = 0; kk < 2; kk++)
        kA[ct][kk] = *(const bf16x8*)(kp + (size_t)(c0 + ct * 16 + lc) * DK + kk * 32 + quad * 8);
    bf16x8 vA[4][4];
#pragma unroll
    for (int kq = 0; kq < 4; kq++)
#pragma unroll
      for (int ct = 0; ct < 4; ct++)
        vA[kq][ct] = *(const bf16x8*)(vp + (size_t)(ct * 16 + lc) * T_TOT + c0 + kq * 32 + quad * 8);

    // S^T = K Q^T over 128 kv: C[kv=ct*16+quad*4+r][q=lc]  (unconditional;
    // out-of-causal-range cols are masked to -inf below, so garbage is safe)
    f32x4 s[8];
#pragma unroll
    for (int ct = 0; ct < 8; ct++) {
      s[ct] = fz;
#pragma unroll
      for (int kk = 0; kk < 2; kk++)
        s[ct] = __builtin_amdgcn_mfma_f32_16x16x32_bf16(kA[ct][kk], qf[kk], s[ct], 0, 0, 0);
    }

    // softmax over 128 kv (in-place in s), 2 cross-quad shuffles per reduce
    float mx = -__builtin_inff();
#pragma unroll
    for (int ct = 0; ct < 8; ct++)
#pragma unroll
      for (int r = 0; r < 4; r++) {
        float v = s[ct][r];
        if (diag && (c0 + ct * 16 + quad * 4 + r) > (q0w + lc)) v = -__builtin_inff();
        s[ct][r] = v;
        mx = fmaxf(mx, v);
      }
    mx = fmaxf(mx, __shfl_xor(mx, 16, 64));
    mx = fmaxf(mx, __shfl_xor(mx, 32, 64));
    float mnew  = fmaxf(m_i, mx);
    float alpha = __expf(m_i - mnew);
    float rs = 0.f;
#pragma unroll
    for (int ct = 0; ct < 8; ct++)
#pragma unroll
      for (int r = 0; r < 4; r++) {
        float pe = __expf(s[ct][r] - mnew);
        s[ct][r] = pe;
        rs += pe;
      }
    rs += __shfl_xor(rs, 16, 64);
    rs += __shfl_xor(rs, 32, 64);
    l_i = l_i * alpha + rs;
    m_i = mnew;
#pragma unroll
    for (int ct = 0; ct < 4; ct++)
#pragma unroll
      for (int r = 0; r < 4; r++) acc_o[ct][r] *= alpha;

    // write P to wave-local LDS: [q=lc][kv], chunk swizzle cc' = cc ^ lc
#pragma unroll
    for (int ct = 0; ct < 8; ct++) {
      bf16x4 pb;
#pragma unroll
      for (int r = 0; r < 4; r++) pb[r] = (__bf16)s[ct][r];
      int cc = ct * 2 + (quad >> 1);
      int el = lc * 128 + ((cc ^ lc) * 8) + (quad & 1) * 4;
      *(bf16x4*)(&Ps[wave][el]) = pb;
    }

    // O^T += V^T P^T (P of masked cols is exactly 0 -> unconditional is correct)
#pragma unroll
    for (int kq = 0; kq < 4; kq++) {
      int cc = kq * 4 + quad;
      bf16x8 pB = *(const bf16x8*)(&Ps[wave][lc * 128 + ((cc ^ lc) * 8)]);
#pragma unroll
      for (int ct = 0; ct < 4; ct++)
        acc_o[ct] = __builtin_amdgcn_mfma_f32_16x16x32_bf16(vA[kq][ct], pB, acc_o[ct], 0, 0, 0);
    }
  }

  // merge 4 partial results (log-sum-exp combine)
  if (wave != 0) {
#pragma unroll
    for (int ct = 0; ct < 4; ct++)
      *(f32x4*)(&OL[wave - 1][((ct * 4 + quad) * 16 + lc) * 4]) = acc_o[ct];
    if (quad == 0) { mlL[wave - 1][0][lc] = m_i; mlL[wave - 1][1][lc] = l_i; }
  }
  __syncthreads();
  if (wave == 0) {
    float mw[3], lw[3];
#pragma unroll
    for (int w = 0; w < 3; w++) { mw[w] = mlL[w][0][lc]; lw[w] = mlL[w][1][lc]; }
    float M = m_i;
#pragma unroll
    for (int w = 0; w < 3; w++) M = fmaxf(M, mw[w]);
    float a0 = __expf(m_i - M);
    float aw[3];
    float Lt = a0 * l_i;
#pragma unroll
    for (int w = 0; w < 3; w++) { aw[w] = __expf(mw[w] - M); Lt += aw[w] * lw[w]; }
    float invl = 1.0f / Lt;
#pragma unroll
    for (int ct = 0; ct < 4; ct++) {
      f32x4 o;
#pragma unroll
      for (int r = 0; r < 4; r++) o[r] = a0 * acc_o[ct][r];
#pragma unroll
      for (int w = 0; w < 3; w++) {
        f32x4 ow = *(const f32x4*)(&OL[w][((ct * 4 + quad) * 16 + lc) * 4]);
#pragma unroll
        for (int r = 0; r < 4; r++) o[r] += aw[w] * ow[r];
      }
#pragma unroll
      for (int r = 0; r < 4; r++) o[r] *= invl;
      *(f32x4*)(&out[((size_t)h * T_TOT + q0w + lc) * DK + ct * 16 + quad * 4]) = o;
    }
  }
}

extern "C" void kernel_launch(void* const* d_in, const int* in_sizes, int n_in,
                              void* d_out, int out_size, void* d_ws, size_t ws_size,
                              hipStream_t stream) {
  const float* x    = (const float*)d_in[0];
  const float* Wq   = (const float*)d_in[1];
  const float* Wk   = (const float*)d_in[2];
  const float* Wv   = (const float*)d_in[3];
  const float* Wqs  = (const float*)d_in[4];
  const float* Wks  = (const float*)d_in[5];
  const float* Wvs  = (const float*)d_in[6];
  const float* scal = (const float*)d_in[7];
  float* out = (float*)d_out;

  char* ws = (char*)d_ws;
  size_t off = 0;
  __bf16* xb  = (__bf16*)(ws + off); off += (size_t)T_TOT * DDIM * 2;
  __bf16* Wt  = (__bf16*)(ws + off); off += (size_t)6 * NH * DK * DDIM * 2;
  __bf16* qkv = (__bf16*)(ws + off); off += (size_t)2 * NH * T_TOT * DK * 2;
  __bf16* vt  = (__bf16*)(ws + off);

  convert_kernel<<<2112, 256, 0, stream>>>(x, Wq, Wk, Wv, Wqs, Wks, Wvs, xb, Wt);
  proj_kernel<<<dim3(3, 18, NH), 256, 0, stream>>>(xb, Wt, scal, qkv, vt);
  attn_kernel<<<dim3(2304), 256, 0, stream>>>(qkv, vt, out);
}